// Round 15
// baseline (130.775 us; speedup 1.0000x reference)
//
#include <hip/hip_runtime.h>
#include <math.h>

typedef _Float16 f16;
typedef _Float16 f16x2 __attribute__((ext_vector_type(2)));
typedef _Float16 f16x4 __attribute__((ext_vector_type(4)));
typedef _Float16 f16x8 __attribute__((ext_vector_type(8)));
typedef float f32x4 __attribute__((ext_vector_type(4)));

#define NROWS (8 * 2048 * 16)   // B*S*G rows of D=64
#define BLOCK 512
#define WAVES 8
#define NITER 4                 // 16-row groups per wave
#define GRID 512                // 512*8 waves * 4 iters * 16 rows = 262144
#define TAU2 5.8e-3f            // rescue threshold, log2 units (r3-validated 4e-3 nats)
#define LOG2E 1.4426950408889634f
#define EXP2F(x) __builtin_amdgcn_exp2f(x)   // glibc reserves __exp2f (r9)

__device__ __forceinline__ f16x2 pkrtz(float a, float b) {
    return __builtin_bit_cast(f16x2, __builtin_amdgcn_cvt_pkrtz(a, b));
}

// One half (160 codes = 10 tiles): acc[10] keeps liveness under the immovable
// 128-VGPR budget (r4-r13 law). Single-limb f16 W (r3-validated with rescue)
// halves W LDS -> total LDS exactly 80KB -> 2 blocks/CU -> 4 waves/SIMD.
// Bias: inline global C-init (L2, 10 loads/half — NOT the r13 hoist pattern).
template <int HB, bool FIRST>
__device__ __forceinline__ void half_pass(
    const f16* __restrict__ Wf, const f16* __restrict__ CVf2,
    const float* __restrict__ bcb,
    const f16x8 (&xh)[2], const f16x8 (&xl)[2],
    int l15, int lg, int wb0, int wb1, int bsb, int cvlo, int cvhi,
    f32x4 (&cv)[4], float& m_run, float& sum_run,
    float& m1o, float& m2o, int& i1o, int& c0, int& c1, int& c2)
{
    // ---- logits (log2-scaled): acc = b*log2e + wh*(xh + xl) ----
    f32x4 acc[10];
    #pragma unroll
    for (int nt = 0; nt < 10; ++nt) {
        const int ntg = HB / 16 + nt;
        f32x4 b4 = *(const f32x4*)&bcb[ntg * 16 + bsb];
        acc[nt] = b4 * LOG2E;
        f16x8 whf0 = *(const f16x8*)&Wf[ntg * 1024 + wb0];
        acc[nt] = __builtin_amdgcn_mfma_f32_16x16x32_f16(whf0, xl[0], acc[nt], 0, 0, 0);
        acc[nt] = __builtin_amdgcn_mfma_f32_16x16x32_f16(whf0, xh[0], acc[nt], 0, 0, 0);
        f16x8 whf1 = *(const f16x8*)&Wf[ntg * 1024 + wb1];
        acc[nt] = __builtin_amdgcn_mfma_f32_16x16x32_f16(whf1, xl[1], acc[nt], 0, 0, 0);
        acc[nt] = __builtin_amdgcn_mfma_f32_16x16x32_f16(whf1, xh[1], acc[nt], 0, 0, 0);
    }

    // ---- top-2 / argmax: two independent chains (half dep depth) ----
    float m1a = -INFINITY, m2a = -INFINITY, m1b = -INFINITY, m2b = -INFINITY;
    int i1a = HB, i1b = HB + 80;
    #pragma unroll
    for (int nt = 0; nt < 5; ++nt) {
        #pragma unroll
        for (int r = 0; r < 4; ++r) {
            float va = acc[nt][r];
            m2a = fmaxf(m2a, fminf(m1a, va));
            if (va > m1a) { m1a = va; i1a = HB + nt * 16 + lg * 4 + r; }
            float vb = acc[nt + 5][r];
            m2b = fmaxf(m2b, fminf(m1b, vb));
            if (vb > m1b) { m1b = vb; i1b = HB + (nt + 5) * 16 + lg * 4 + r; }
        }
    }
    float m2 = fmaxf(fmaxf(m2a, m2b), fminf(m1a, m1b));
    float m1 = m1a;
    int i1 = i1a;
    if (m1b > m1) { m1 = m1b; i1 = i1b; }   // tie -> chain a (lower codes)
    #pragma unroll
    for (int dx = 16; dx <= 32; dx <<= 1) {
        float mo = __shfl_xor(m1, dx, 64);
        int io = __shfl_xor(i1, dx, 64);
        float m2x = __shfl_xor(m2, dx, 64);
        m2 = fmaxf(fmaxf(m2, m2x), fminf(m1, mo));
        if (mo > m1 || (mo == m1 && io < i1)) { m1 = mo; i1 = io; }
    }

    // ---- candidate collection, gated on per-half near-tie ----
    c0 = -1; c1 = -1; c2 = -1;
    if (m1 - m2 < TAU2) {
        const float thr = m1 - TAU2;
        #pragma unroll
        for (int nt = 0; nt < 10; ++nt) {
            #pragma unroll
            for (int r = 0; r < 4; ++r) {
                if (acc[nt][r] >= thr) {
                    int c = HB + nt * 16 + lg * 4 + r;
                    if (c0 < 0) c0 = c;
                    else if (c1 < 0) c1 = c;
                    else if (c2 < 0) c2 = c;
                }
            }
        }
    }

    // ---- online-softmax merge (base-2) ----
    float mnew = m1;
    if (!FIRST) {
        mnew = fmaxf(m_run, m1);
        float sc = EXP2F(m_run - mnew);
        sum_run *= sc;
        #pragma unroll
        for (int dt = 0; dt < 4; ++dt) {
            cv[dt][0] *= sc; cv[dt][1] *= sc; cv[dt][2] *= sc; cv[dt][3] *= sc;
        }
    }

    // ---- fused exp + PV (4 partial sums; MFMA overlaps exp chain) ----
    float sA = 0.f, sB = 0.f, sC = 0.f, sD = 0.f;
    #pragma unroll
    for (int nt = 0; nt < 10; ++nt) {
        const int ntg = HB / 16 + nt;
        float p0 = EXP2F(acc[nt][0] - mnew);
        float p1 = EXP2F(acc[nt][1] - mnew);
        float p2 = EXP2F(acc[nt][2] - mnew);
        float p3 = EXP2F(acc[nt][3] - mnew);
        sA += p0; sB += p1; sC += p2; sD += p3;
        f16x2 plo = pkrtz(p0, p1);
        f16x2 phi = pkrtz(p2, p3);
        f16x4 pf = {plo[0], plo[1], phi[0], phi[1]};
        f16x8 lo = *(const f16x8*)&CVf2[ntg * 1024 + cvlo];   // dt0,dt1
        f16x8 hi = *(const f16x8*)&CVf2[ntg * 1024 + cvhi];   // dt2,dt3
        f16x4 cf0 = __builtin_shufflevector(lo, lo, 0, 1, 2, 3);
        f16x4 cf1 = __builtin_shufflevector(lo, lo, 4, 5, 6, 7);
        f16x4 cf2 = __builtin_shufflevector(hi, hi, 0, 1, 2, 3);
        f16x4 cf3 = __builtin_shufflevector(hi, hi, 4, 5, 6, 7);
        cv[0] = __builtin_amdgcn_mfma_f32_16x16x16f16(cf0, pf, cv[0], 0, 0, 0);
        cv[1] = __builtin_amdgcn_mfma_f32_16x16x16f16(cf1, pf, cv[1], 0, 0, 0);
        cv[2] = __builtin_amdgcn_mfma_f32_16x16x16f16(cf2, pf, cv[2], 0, 0, 0);
        cv[3] = __builtin_amdgcn_mfma_f32_16x16x16f16(cf3, pf, cv[3], 0, 0, 0);
    }
    float s = (sA + sB) + (sC + sD);
    sum_run = FIRST ? s : (sum_run + s);
    m_run = mnew;
    m1o = m1; m2o = m2; i1o = i1;
}

__global__ __launch_bounds__(BLOCK) void vq_mfma(
    const float* __restrict__ inputs,   // [262144][64]
    const int* __restrict__ mask,       // [16384]
    const float* __restrict__ Wcb,      // [64][320] raw (staging + rescue)
    const float* __restrict__ bcb,      // [320] raw (C-init + rescue)
    const float* __restrict__ codevec,  // [320][64]
    float* __restrict__ out_cv,         // [262144][64]
    float* __restrict__ out_cw)         // [262144] as float
{
    // Exactly 80 KB LDS -> 2 blocks/CU (160 KB pool) -> 4 waves/SIMD.
    // W^T f16 single limb (log2e-scaled), swizzled: slot' = slot ^ (n&7)
    __shared__ __align__(16) f16 Wf[320 * 64];
    // CV^T f16, dt-contiguous: idx = ntg*1024 + l15*64 + ((lg*2+s)^l7)*8
    //   + (dt&1)*4 + r  (conflict-free b128 reads: 8 lanes per 4-bank group)
    __shared__ __align__(16) f16 CVf2[20 * 1024];

    const int tid = threadIdx.x;

    // W staging: n-major (conflict-free LDS writes; reads L2-resident)
    for (int e = tid; e < 64 * 320; e += BLOCK) {
        int n = e >> 6, d = e & 63;
        float w = Wcb[d * 320 + n] * LOG2E;
        int s = d >> 3;
        Wf[n * 64 + (((s ^ n) & 7) << 3) + (d & 7)] = (f16)w;
    }
    for (int e = tid; e < 320 * 64; e += BLOCK) {
        int c = e >> 6, d = e & 63;       // codevec [320][64] k-major
        int lgs = (c >> 2) & 3, s = (d >> 5) & 1;
        int slot = (lgs * 2 + s) ^ (d & 7);
        CVf2[(c >> 4) * 1024 + (d & 15) * 64 + slot * 8 + ((d >> 4) & 1) * 4 + (c & 3)] =
            (f16)codevec[e];
    }
    __syncthreads();

    const int wid = tid >> 6;
    const int lane = tid & 63;
    const int l15 = lane & 15;          // C column = data row
    const int lg = lane >> 4;           // frag k-group 0..3
    const int l7 = l15 & 7;
    const int u = blockIdx.x * WAVES + wid;   // 0..4095

    // it-invariant LDS element bases
    const int wb0 = l15 * 64 + (((lg ^ l7) & 7) << 3);          // kc=0
    const int wb1 = l15 * 64 + ((((4 + lg) ^ l7) & 7) << 3);    // kc=1
    const int bsb = lg * 4;
    const int cvlo = l15 * 64 + (((lg * 2) ^ l7) << 3);         // s=0
    const int cvhi = l15 * 64 + (((lg * 2 + 1) ^ l7) << 3);     // s=1

    #pragma unroll 1
    for (int it = 0; it < NITER; ++it) {
        const int row0 = u * (NITER * 16) + it * 16;
        const float* xrow = inputs + (size_t)(row0 + l15) * 64;

        // ---- x B-frags, 2 f16 limbs (xl subnormal flush bounded ~4e-6/elem) ----
        f16x8 xh[2], xl[2];
        #pragma unroll
        for (int kc = 0; kc < 2; ++kc) {
            float4 a = *(const float4*)(xrow + kc * 32 + lg * 8);
            float4 b = *(const float4*)(xrow + kc * 32 + lg * 8 + 4);
            float xv[8] = {a.x, a.y, a.z, a.w, b.x, b.y, b.z, b.w};
            f16x8 h, l;
            #pragma unroll
            for (int e = 0; e < 8; ++e) {
                f16 hh = (f16)xv[e];
                h[e] = hh;
                l[e] = (f16)(xv[e] - (float)hh);
            }
            xh[kc] = h;
            xl[kc] = l;
        }

        f32x4 cv[4];
        #pragma unroll
        for (int dt = 0; dt < 4; ++dt) cv[dt] = (f32x4){0.f, 0.f, 0.f, 0.f};
        float m_run = 0.f, sum_run = 0.f;
        float m1A, m2A, m1B, m2B;
        int i1A, i1B, cA0, cA1, cA2, cB0, cB1, cB2;

        half_pass<0, true>(Wf, CVf2, bcb, xh, xl, l15, lg,
                           wb0, wb1, bsb, cvlo, cvhi,
                           cv, m_run, sum_run, m1A, m2A, i1A, cA0, cA1, cA2);
        half_pass<160, false>(Wf, CVf2, bcb, xh, xl, l15, lg,
                              wb0, wb1, bsb, cvlo, cvhi,
                              cv, m_run, sum_run, m1B, m2B, i1B, cB0, cB1, cB2);

        // ---- merge halves: global top-2 / argmax ----
        float m1 = m1A;
        int i1 = i1A;
        float m2 = fmaxf(fmaxf(m2A, m2B), fminf(m1A, m1B));
        if (m1B > m1) { m1 = m1B; i1 = i1B; }   // tie -> half A (smaller index)

        float sum = sum_run;
        sum += __shfl_xor(sum, 16, 64);
        sum += __shfl_xor(sum, 32, 64);

        // ---- exact-argmax rescue for near-ties (raw f32, nat units) ----
        // fmaf order (bias first, d ascending) preserved from r3-r14.
        const int mk = mask[u * NITER + it];   // wave-uniform
        int cw = i1;
        const bool flag = mk && (m1 - m2 < TAU2);
        if (__any(flag)) {
            float bv = -INFINITY;
            int bi = 0x7fffffff;
            #pragma unroll 1
            for (int t = 0; t < 8; ++t) {
                int c = (t == 0) ? i1A : (t == 1) ? i1B :
                        (t == 2) ? cA0 : (t == 3) ? cA1 : (t == 4) ? cA2 :
                        (t == 5) ? cB0 : (t == 6) ? cB1 : cB2;
                if (!flag) c = -1;
                if (__any(c >= 0)) {
                    if (c >= 0) {
                        float sacc = bcb[c];
                        #pragma unroll 4
                        for (int q = 0; q < 16; ++q) {
                            float4 xv4 = *(const float4*)(xrow + q * 4);
                            sacc = fmaf(xv4.x, Wcb[(q * 4 + 0) * 320 + c], sacc);
                            sacc = fmaf(xv4.y, Wcb[(q * 4 + 1) * 320 + c], sacc);
                            sacc = fmaf(xv4.z, Wcb[(q * 4 + 2) * 320 + c], sacc);
                            sacc = fmaf(xv4.w, Wcb[(q * 4 + 3) * 320 + c], sacc);
                        }
                        if (sacc > bv || (sacc == bv && c < bi)) { bv = sacc; bi = c; }
                    }
                }
            }
            #pragma unroll
            for (int dx = 16; dx <= 32; dx <<= 1) {
                float vo = __shfl_xor(bv, dx, 64);
                int io = __shfl_xor(bi, dx, 64);
                if (vo > bv || (vo == bv && io < bi)) { bv = vo; bi = io; }
            }
            if (flag) cw = bi;
        }

        // ---- epilogue: mask, normalize, store ----
        const float inv = mk ? (1.0f / sum) : 0.0f;
        float* orow = out_cv + (size_t)(row0 + l15) * 64;
        #pragma unroll
        for (int dt = 0; dt < 4; ++dt) {
            f32x4 v;
            v[0] = cv[dt][0] * inv;
            v[1] = cv[dt][1] * inv;
            v[2] = cv[dt][2] * inv;
            v[3] = cv[dt][3] * inv;
            *(f32x4*)(orow + dt * 16 + lg * 4) = v;
        }
        if (lg == 0) out_cw[row0 + l15] = mk ? (float)cw : 0.0f;
    }
}

extern "C" void kernel_launch(void* const* d_in, const int* in_sizes, int n_in,
                              void* d_out, int out_size, void* d_ws, size_t ws_size,
                              hipStream_t stream) {
    const float* inputs  = (const float*)d_in[0];
    const int*   mask    = (const int*)d_in[1];
    const float* Wcb     = (const float*)d_in[2];
    const float* bcb     = (const float*)d_in[3];
    const float* codevec = (const float*)d_in[4];

    float* out_cv = (float*)d_out;
    float* out_cw = out_cv + (size_t)NROWS * 64;

    vq_mfma<<<GRID, BLOCK, 0, stream>>>(inputs, mask, Wcb, bcb, codevec,
                                        out_cv, out_cw);
}

// Round 16
// 124.357 us; speedup vs baseline: 1.0516x; 1.0516x over previous
//
#include <hip/hip_runtime.h>
#include <math.h>

typedef _Float16 f16;
typedef _Float16 f16x2 __attribute__((ext_vector_type(2)));
typedef _Float16 f16x4 __attribute__((ext_vector_type(4)));
typedef _Float16 f16x8 __attribute__((ext_vector_type(8)));
typedef float f32x4 __attribute__((ext_vector_type(4)));

#define NROWS (8 * 2048 * 16)   // B*S*G rows of D=64
#define BLOCK 512
#define WAVES 8
#define NITER 4                 // 16-row groups per wave
#define GRID 512                // 512*8 waves * 4 iters * 16 rows = 262144
#define TAU2 5.8e-3f            // rescue threshold, log2 units (r3-validated 4e-3 nats)
#define LOG2E 1.4426950408889634f
#define EXP2F(x) __builtin_amdgcn_exp2f(x)   // glibc reserves __exp2f (r9)

__device__ __forceinline__ f16x2 pkrtz(float a, float b) {
    return __builtin_bit_cast(f16x2, __builtin_amdgcn_cvt_pkrtz(a, b));
}

// One half (160 codes = 10 tiles): acc[10] keeps liveness under the immovable
// 128-VGPR budget (r4-r13 law). Single-limb f16 W (r3-validated with rescue).
// ALL hot-loop operands from LDS — r15 proved bias-from-global stalls ~35us
// (per-tile vmcnt chains at 2 waves/SIMD).
template <int HB, bool FIRST>
__device__ __forceinline__ void half_pass(
    const f16* __restrict__ Wf, const f16* __restrict__ CVf2,
    const float* __restrict__ bs,
    const f16x8 (&xh)[2], const f16x8 (&xl)[2],
    int l15, int lg, int wb0, int wb1, int bsb, int cvlo, int cvhi,
    f32x4 (&cv)[4], float& m_run, float& sum_run,
    float& m1o, float& m2o, int& i1o, int& c0, int& c1, int& c2)
{
    // ---- logits (log2-scaled): acc = b2 + wh*(xh + xl) ----
    f32x4 acc[10];
    #pragma unroll
    for (int nt = 0; nt < 10; ++nt) {
        const int ntg = HB / 16 + nt;
        acc[nt] = *(const f32x4*)&bs[ntg * 16 + bsb];   // bias C-init (LDS)
        f16x8 whf0 = *(const f16x8*)&Wf[ntg * 1024 + wb0];
        acc[nt] = __builtin_amdgcn_mfma_f32_16x16x32_f16(whf0, xl[0], acc[nt], 0, 0, 0);
        acc[nt] = __builtin_amdgcn_mfma_f32_16x16x32_f16(whf0, xh[0], acc[nt], 0, 0, 0);
        f16x8 whf1 = *(const f16x8*)&Wf[ntg * 1024 + wb1];
        acc[nt] = __builtin_amdgcn_mfma_f32_16x16x32_f16(whf1, xl[1], acc[nt], 0, 0, 0);
        acc[nt] = __builtin_amdgcn_mfma_f32_16x16x32_f16(whf1, xh[1], acc[nt], 0, 0, 0);
    }

    // ---- top-2 / argmax: two independent chains (half dep depth) ----
    float m1a = -INFINITY, m2a = -INFINITY, m1b = -INFINITY, m2b = -INFINITY;
    int i1a = HB, i1b = HB + 80;
    #pragma unroll
    for (int nt = 0; nt < 5; ++nt) {
        #pragma unroll
        for (int r = 0; r < 4; ++r) {
            float va = acc[nt][r];
            m2a = fmaxf(m2a, fminf(m1a, va));
            if (va > m1a) { m1a = va; i1a = HB + nt * 16 + lg * 4 + r; }
            float vb = acc[nt + 5][r];
            m2b = fmaxf(m2b, fminf(m1b, vb));
            if (vb > m1b) { m1b = vb; i1b = HB + (nt + 5) * 16 + lg * 4 + r; }
        }
    }
    float m2 = fmaxf(fmaxf(m2a, m2b), fminf(m1a, m1b));
    float m1 = m1a;
    int i1 = i1a;
    if (m1b > m1) { m1 = m1b; i1 = i1b; }   // tie -> chain a (lower codes)
    #pragma unroll
    for (int dx = 16; dx <= 32; dx <<= 1) {
        float mo = __shfl_xor(m1, dx, 64);
        int io = __shfl_xor(i1, dx, 64);
        float m2x = __shfl_xor(m2, dx, 64);
        m2 = fmaxf(fmaxf(m2, m2x), fminf(m1, mo));
        if (mo > m1 || (mo == m1 && io < i1)) { m1 = mo; i1 = io; }
    }

    // ---- candidate collection, gated on per-half near-tie ----
    c0 = -1; c1 = -1; c2 = -1;
    if (m1 - m2 < TAU2) {
        const float thr = m1 - TAU2;
        #pragma unroll
        for (int nt = 0; nt < 10; ++nt) {
            #pragma unroll
            for (int r = 0; r < 4; ++r) {
                if (acc[nt][r] >= thr) {
                    int c = HB + nt * 16 + lg * 4 + r;
                    if (c0 < 0) c0 = c;
                    else if (c1 < 0) c1 = c;
                    else if (c2 < 0) c2 = c;
                }
            }
        }
    }

    // ---- online-softmax merge (base-2) ----
    float mnew = m1;
    if (!FIRST) {
        mnew = fmaxf(m_run, m1);
        float sc = EXP2F(m_run - mnew);
        sum_run *= sc;
        #pragma unroll
        for (int dt = 0; dt < 4; ++dt) {
            cv[dt][0] *= sc; cv[dt][1] *= sc; cv[dt][2] *= sc; cv[dt][3] *= sc;
        }
    }

    // ---- fused exp + PV (4 partial sums; MFMA overlaps exp chain) ----
    float sA = 0.f, sB = 0.f, sC = 0.f, sD = 0.f;
    #pragma unroll
    for (int nt = 0; nt < 10; ++nt) {
        const int ntg = HB / 16 + nt;
        float p0 = EXP2F(acc[nt][0] - mnew);
        float p1 = EXP2F(acc[nt][1] - mnew);
        float p2 = EXP2F(acc[nt][2] - mnew);
        float p3 = EXP2F(acc[nt][3] - mnew);
        sA += p0; sB += p1; sC += p2; sD += p3;
        f16x2 plo = pkrtz(p0, p1);
        f16x2 phi = pkrtz(p2, p3);
        f16x4 pf = {plo[0], plo[1], phi[0], phi[1]};
        f16x8 lo = *(const f16x8*)&CVf2[ntg * 1024 + cvlo];   // dt0,dt1
        f16x8 hi = *(const f16x8*)&CVf2[ntg * 1024 + cvhi];   // dt2,dt3
        f16x4 cf0 = __builtin_shufflevector(lo, lo, 0, 1, 2, 3);
        f16x4 cf1 = __builtin_shufflevector(lo, lo, 4, 5, 6, 7);
        f16x4 cf2 = __builtin_shufflevector(hi, hi, 0, 1, 2, 3);
        f16x4 cf3 = __builtin_shufflevector(hi, hi, 4, 5, 6, 7);
        cv[0] = __builtin_amdgcn_mfma_f32_16x16x16f16(cf0, pf, cv[0], 0, 0, 0);
        cv[1] = __builtin_amdgcn_mfma_f32_16x16x16f16(cf1, pf, cv[1], 0, 0, 0);
        cv[2] = __builtin_amdgcn_mfma_f32_16x16x16f16(cf2, pf, cv[2], 0, 0, 0);
        cv[3] = __builtin_amdgcn_mfma_f32_16x16x16f16(cf3, pf, cv[3], 0, 0, 0);
    }
    float s = (sA + sB) + (sC + sD);
    sum_run = FIRST ? s : (sum_run + s);
    m_run = mnew;
    m1o = m1; m2o = m2; i1o = i1;
}

__global__ __launch_bounds__(BLOCK) void vq_mfma(
    const float* __restrict__ inputs,   // [262144][64]
    const int* __restrict__ mask,       // [16384]
    const float* __restrict__ Wcb,      // [64][320] raw (staging + rescue)
    const float* __restrict__ bcb,      // [320] raw (staging + rescue)
    const float* __restrict__ codevec,  // [320][64]
    float* __restrict__ out_cv,         // [262144][64]
    float* __restrict__ out_cw)         // [262144] as float
{
    // 83.2 KB LDS (1 block/CU — 2x80KB proven not to co-reside in r15).
    // W^T f16 single limb (log2e-scaled), swizzled: slot' = slot ^ (n&7)
    __shared__ __align__(16) f16 Wf[320 * 64];
    // CV^T f16, dt-contiguous: idx = ntg*1024 + l15*64 + ((lg*2+s)^l7)*8
    //   + (dt&1)*4 + r  (conflict-free b128 reads: 8 lanes per 4-bank group)
    __shared__ __align__(16) f16 CVf2[20 * 1024];
    __shared__ __align__(16) float bs[320];    // bias * log2e

    const int tid = threadIdx.x;

    // W staging: n-major (conflict-free LDS writes; reads L2-resident)
    for (int e = tid; e < 64 * 320; e += BLOCK) {
        int n = e >> 6, d = e & 63;
        float w = Wcb[d * 320 + n] * LOG2E;
        int s = d >> 3;
        Wf[n * 64 + (((s ^ n) & 7) << 3) + (d & 7)] = (f16)w;
    }
    for (int e = tid; e < 320 * 64; e += BLOCK) {
        int c = e >> 6, d = e & 63;       // codevec [320][64] k-major
        int lgs = (c >> 2) & 3, s = (d >> 5) & 1;
        int slot = (lgs * 2 + s) ^ (d & 7);
        CVf2[(c >> 4) * 1024 + (d & 15) * 64 + slot * 8 + ((d >> 4) & 1) * 4 + (c & 3)] =
            (f16)codevec[e];
    }
    for (int e = tid; e < 320; e += BLOCK) bs[e] = bcb[e] * LOG2E;
    __syncthreads();

    const int wid = tid >> 6;
    const int lane = tid & 63;
    const int l15 = lane & 15;          // C column = data row
    const int lg = lane >> 4;           // frag k-group 0..3
    const int l7 = l15 & 7;
    const int u = blockIdx.x * WAVES + wid;   // 0..4095

    // it-invariant LDS element bases
    const int wb0 = l15 * 64 + (((lg ^ l7) & 7) << 3);          // kc=0
    const int wb1 = l15 * 64 + ((((4 + lg) ^ l7) & 7) << 3);    // kc=1
    const int bsb = lg * 4;
    const int cvlo = l15 * 64 + (((lg * 2) ^ l7) << 3);         // s=0
    const int cvhi = l15 * 64 + (((lg * 2 + 1) ^ l7) << 3);     // s=1

    #pragma unroll 1
    for (int it = 0; it < NITER; ++it) {
        const int row0 = u * (NITER * 16) + it * 16;
        const float* xrow = inputs + (size_t)(row0 + l15) * 64;

        // ---- x B-frags, 2 f16 limbs (xl subnormal flush bounded ~4e-6/elem) ----
        f16x8 xh[2], xl[2];
        #pragma unroll
        for (int kc = 0; kc < 2; ++kc) {
            float4 a = *(const float4*)(xrow + kc * 32 + lg * 8);
            float4 b = *(const float4*)(xrow + kc * 32 + lg * 8 + 4);
            float xv[8] = {a.x, a.y, a.z, a.w, b.x, b.y, b.z, b.w};
            f16x8 h, l;
            #pragma unroll
            for (int e = 0; e < 8; ++e) {
                f16 hh = (f16)xv[e];
                h[e] = hh;
                l[e] = (f16)(xv[e] - (float)hh);
            }
            xh[kc] = h;
            xl[kc] = l;
        }

        f32x4 cv[4];
        #pragma unroll
        for (int dt = 0; dt < 4; ++dt) cv[dt] = (f32x4){0.f, 0.f, 0.f, 0.f};
        float m_run = 0.f, sum_run = 0.f;
        float m1A, m2A, m1B, m2B;
        int i1A, i1B, cA0, cA1, cA2, cB0, cB1, cB2;

        half_pass<0, true>(Wf, CVf2, bs, xh, xl, l15, lg,
                           wb0, wb1, bsb, cvlo, cvhi,
                           cv, m_run, sum_run, m1A, m2A, i1A, cA0, cA1, cA2);
        half_pass<160, false>(Wf, CVf2, bs, xh, xl, l15, lg,
                              wb0, wb1, bsb, cvlo, cvhi,
                              cv, m_run, sum_run, m1B, m2B, i1B, cB0, cB1, cB2);

        // ---- merge halves: global top-2 / argmax ----
        float m1 = m1A;
        int i1 = i1A;
        float m2 = fmaxf(fmaxf(m2A, m2B), fminf(m1A, m1B));
        if (m1B > m1) { m1 = m1B; i1 = i1B; }   // tie -> half A (smaller index)

        float sum = sum_run;
        sum += __shfl_xor(sum, 16, 64);
        sum += __shfl_xor(sum, 32, 64);

        // ---- exact-argmax rescue for near-ties (raw f32, nat units) ----
        // fmaf order (bias first, d ascending) preserved from r3-r15.
        const int mk = mask[u * NITER + it];   // wave-uniform
        int cw = i1;
        const bool flag = mk && (m1 - m2 < TAU2);
        if (__any(flag)) {
            float bv = -INFINITY;
            int bi = 0x7fffffff;
            #pragma unroll 1
            for (int t = 0; t < 8; ++t) {
                int c = (t == 0) ? i1A : (t == 1) ? i1B :
                        (t == 2) ? cA0 : (t == 3) ? cA1 : (t == 4) ? cA2 :
                        (t == 5) ? cB0 : (t == 6) ? cB1 : cB2;
                if (!flag) c = -1;
                if (__any(c >= 0)) {
                    if (c >= 0) {
                        float sacc = bcb[c];
                        #pragma unroll 4
                        for (int q = 0; q < 16; ++q) {
                            float4 xv4 = *(const float4*)(xrow + q * 4);
                            sacc = fmaf(xv4.x, Wcb[(q * 4 + 0) * 320 + c], sacc);
                            sacc = fmaf(xv4.y, Wcb[(q * 4 + 1) * 320 + c], sacc);
                            sacc = fmaf(xv4.z, Wcb[(q * 4 + 2) * 320 + c], sacc);
                            sacc = fmaf(xv4.w, Wcb[(q * 4 + 3) * 320 + c], sacc);
                        }
                        if (sacc > bv || (sacc == bv && c < bi)) { bv = sacc; bi = c; }
                    }
                }
            }
            #pragma unroll
            for (int dx = 16; dx <= 32; dx <<= 1) {
                float vo = __shfl_xor(bv, dx, 64);
                int io = __shfl_xor(bi, dx, 64);
                if (vo > bv || (vo == bv && io < bi)) { bv = vo; bi = io; }
            }
            if (flag) cw = bi;
        }

        // ---- epilogue: mask, normalize, store ----
        const float inv = mk ? (1.0f / sum) : 0.0f;
        float* orow = out_cv + (size_t)(row0 + l15) * 64;
        #pragma unroll
        for (int dt = 0; dt < 4; ++dt) {
            f32x4 v;
            v[0] = cv[dt][0] * inv;
            v[1] = cv[dt][1] * inv;
            v[2] = cv[dt][2] * inv;
            v[3] = cv[dt][3] * inv;
            *(f32x4*)(orow + dt * 16 + lg * 4) = v;
        }
        if (lg == 0) out_cw[row0 + l15] = mk ? (float)cw : 0.0f;
    }
}

extern "C" void kernel_launch(void* const* d_in, const int* in_sizes, int n_in,
                              void* d_out, int out_size, void* d_ws, size_t ws_size,
                              hipStream_t stream) {
    const float* inputs  = (const float*)d_in[0];
    const int*   mask    = (const int*)d_in[1];
    const float* Wcb     = (const float*)d_in[2];
    const float* bcb     = (const float*)d_in[3];
    const float* codevec = (const float*)d_in[4];

    float* out_cv = (float*)d_out;
    float* out_cw = out_cv + (size_t)NROWS * 64;

    vq_mfma<<<GRID, BLOCK, 0, stream>>>(inputs, mask, Wcb, bcb, codevec,
                                        out_cv, out_cw);
}

// Round 17
// 86.899 us; speedup vs baseline: 1.5049x; 1.4311x over previous
//
#include <hip/hip_runtime.h>
#include <math.h>

typedef _Float16 f16;
typedef _Float16 f16x2 __attribute__((ext_vector_type(2)));
typedef _Float16 f16x4 __attribute__((ext_vector_type(4)));
typedef _Float16 f16x8 __attribute__((ext_vector_type(8)));
typedef short short8 __attribute__((ext_vector_type(8)));
typedef float f32x4 __attribute__((ext_vector_type(4)));

#define NROWS (8 * 2048 * 16)   // B*S*G rows of D=64
#define BLOCK 512
#define WAVES 8
#define NITER 8                 // 16-row groups per wave (r17: 8, one block/CU)
#define GRID 256                // 256 blocks = 1 per CU -> staging paid ONCE
#define TAU2 4.4e-4f            // rescue threshold in log2 units (=3e-4 nats)
#define LOG2E 1.4426950408889634f
#define EXP2F(x) __builtin_amdgcn_exp2f(x)   // glibc reserves __exp2f (r9)

__device__ __forceinline__ short f2bf(float f) {
    unsigned u = __builtin_bit_cast(unsigned, f);
    return (short)((u + 0x7fffu + ((u >> 16) & 1u)) >> 16);
}
__device__ __forceinline__ float bf2f(short h) {
    return __builtin_bit_cast(float, ((unsigned)(unsigned short)h) << 16);
}
__device__ __forceinline__ f16x2 pkrtz(float a, float b) {
    return __builtin_bit_cast(f16x2, __builtin_amdgcn_cvt_pkrtz(a, b));
}

// One half (160 codes = 10 tiles): acc[10] keeps liveness under the immovable
// 128-VGPR budget (r4-r13 law). 2-limb bf16 W (logit err ~5e-6 -> rescue rare;
// r16 proved single-limb's frequent rescue costs ~30us). All hot operands LDS.
template <int HB, bool FIRST>
__device__ __forceinline__ void half_pass(
    const short* __restrict__ Wh, const short* __restrict__ Wl,
    const f16* __restrict__ CVf2, const float* __restrict__ bs,
    const short8 (&xh)[2], const short8 (&xl)[2],
    int l15, int lg, int wb0, int wb1, int bsb, int cvlo, int cvhi,
    f32x4 (&cv)[4], float& m_run, float& sum_run,
    float& m1o, float& m2o, int& i1o, int& c0, int& c1, int& c2)
{
    // ---- logits (log2-scaled): acc = b2 + wh*xh + wh*xl + wl*xh ----
    f32x4 acc[10];
    #pragma unroll
    for (int nt = 0; nt < 10; ++nt) {
        const int ntg = HB / 16 + nt;
        acc[nt] = *(const f32x4*)&bs[ntg * 16 + bsb];   // bias C-init
        short8 whf0 = *(const short8*)&Wh[ntg * 1024 + wb0];
        short8 wlf0 = *(const short8*)&Wl[ntg * 1024 + wb0];
        acc[nt] = __builtin_amdgcn_mfma_f32_16x16x32_bf16(whf0, xl[0], acc[nt], 0, 0, 0);
        acc[nt] = __builtin_amdgcn_mfma_f32_16x16x32_bf16(wlf0, xh[0], acc[nt], 0, 0, 0);
        acc[nt] = __builtin_amdgcn_mfma_f32_16x16x32_bf16(whf0, xh[0], acc[nt], 0, 0, 0);
        short8 whf1 = *(const short8*)&Wh[ntg * 1024 + wb1];
        short8 wlf1 = *(const short8*)&Wl[ntg * 1024 + wb1];
        acc[nt] = __builtin_amdgcn_mfma_f32_16x16x32_bf16(whf1, xl[1], acc[nt], 0, 0, 0);
        acc[nt] = __builtin_amdgcn_mfma_f32_16x16x32_bf16(wlf1, xh[1], acc[nt], 0, 0, 0);
        acc[nt] = __builtin_amdgcn_mfma_f32_16x16x32_bf16(whf1, xh[1], acc[nt], 0, 0, 0);
    }

    // ---- top-2 / argmax: two independent chains (half dep depth) ----
    float m1a = -INFINITY, m2a = -INFINITY, m1b = -INFINITY, m2b = -INFINITY;
    int i1a = HB, i1b = HB + 80;
    #pragma unroll
    for (int nt = 0; nt < 5; ++nt) {
        #pragma unroll
        for (int r = 0; r < 4; ++r) {
            float va = acc[nt][r];
            m2a = fmaxf(m2a, fminf(m1a, va));
            if (va > m1a) { m1a = va; i1a = HB + nt * 16 + lg * 4 + r; }
            float vb = acc[nt + 5][r];
            m2b = fmaxf(m2b, fminf(m1b, vb));
            if (vb > m1b) { m1b = vb; i1b = HB + (nt + 5) * 16 + lg * 4 + r; }
        }
    }
    float m2 = fmaxf(fmaxf(m2a, m2b), fminf(m1a, m1b));
    float m1 = m1a;
    int i1 = i1a;
    if (m1b > m1) { m1 = m1b; i1 = i1b; }   // tie -> chain a (lower codes)
    #pragma unroll
    for (int dx = 16; dx <= 32; dx <<= 1) {
        float mo = __shfl_xor(m1, dx, 64);
        int io = __shfl_xor(i1, dx, 64);
        float m2x = __shfl_xor(m2, dx, 64);
        m2 = fmaxf(fmaxf(m2, m2x), fminf(m1, mo));
        if (mo > m1 || (mo == m1 && io < i1)) { m1 = mo; i1 = io; }
    }

    // ---- candidate collection, gated on per-half near-tie ----
    c0 = -1; c1 = -1; c2 = -1;
    if (m1 - m2 < TAU2) {
        const float thr = m1 - TAU2;
        #pragma unroll
        for (int nt = 0; nt < 10; ++nt) {
            #pragma unroll
            for (int r = 0; r < 4; ++r) {
                if (acc[nt][r] >= thr) {
                    int c = HB + nt * 16 + lg * 4 + r;
                    if (c0 < 0) c0 = c;
                    else if (c1 < 0) c1 = c;
                    else if (c2 < 0) c2 = c;
                }
            }
        }
    }

    // ---- online-softmax merge (base-2) ----
    float mnew = m1;
    if (!FIRST) {
        mnew = fmaxf(m_run, m1);
        float sc = EXP2F(m_run - mnew);
        sum_run *= sc;
        #pragma unroll
        for (int dt = 0; dt < 4; ++dt) {
            cv[dt][0] *= sc; cv[dt][1] *= sc; cv[dt][2] *= sc; cv[dt][3] *= sc;
        }
    }

    // ---- fused exp + PV (4 partial sums; MFMA overlaps exp chain) ----
    float sA = 0.f, sB = 0.f, sC = 0.f, sD = 0.f;
    #pragma unroll
    for (int nt = 0; nt < 10; ++nt) {
        const int ntg = HB / 16 + nt;
        float p0 = EXP2F(acc[nt][0] - mnew);
        float p1 = EXP2F(acc[nt][1] - mnew);
        float p2 = EXP2F(acc[nt][2] - mnew);
        float p3 = EXP2F(acc[nt][3] - mnew);
        sA += p0; sB += p1; sC += p2; sD += p3;
        f16x2 plo = pkrtz(p0, p1);
        f16x2 phi = pkrtz(p2, p3);
        f16x4 pf = {plo[0], plo[1], phi[0], phi[1]};
        f16x8 lo = *(const f16x8*)&CVf2[ntg * 1024 + cvlo];   // dt0,dt1
        f16x8 hi = *(const f16x8*)&CVf2[ntg * 1024 + cvhi];   // dt2,dt3
        f16x4 cf0 = __builtin_shufflevector(lo, lo, 0, 1, 2, 3);
        f16x4 cf1 = __builtin_shufflevector(lo, lo, 4, 5, 6, 7);
        f16x4 cf2 = __builtin_shufflevector(hi, hi, 0, 1, 2, 3);
        f16x4 cf3 = __builtin_shufflevector(hi, hi, 4, 5, 6, 7);
        cv[0] = __builtin_amdgcn_mfma_f32_16x16x16f16(cf0, pf, cv[0], 0, 0, 0);
        cv[1] = __builtin_amdgcn_mfma_f32_16x16x16f16(cf1, pf, cv[1], 0, 0, 0);
        cv[2] = __builtin_amdgcn_mfma_f32_16x16x16f16(cf2, pf, cv[2], 0, 0, 0);
        cv[3] = __builtin_amdgcn_mfma_f32_16x16x16f16(cf3, pf, cv[3], 0, 0, 0);
    }
    float s = (sA + sB) + (sC + sD);
    sum_run = FIRST ? s : (sum_run + s);
    m_run = mnew;
    m1o = m1; m2o = m2; i1o = i1;
}

__global__ __launch_bounds__(BLOCK) void vq_mfma(
    const float* __restrict__ inputs,   // [262144][64]
    const int* __restrict__ mask,       // [16384]
    const float* __restrict__ Wcb,      // [64][320] raw (staging + rescue)
    const float* __restrict__ bcb,      // [320] raw (rescue)
    const float* __restrict__ codevec,  // [320][64]
    float* __restrict__ out_cv,         // [262144][64]
    float* __restrict__ out_cw)         // [262144] as float
{
    // W^T bf16 limbs (log2e-scaled), swizzled: slot' = slot ^ (n&7)
    __shared__ __align__(16) short Wh[320 * 64];
    __shared__ __align__(16) short Wl[320 * 64];
    // CV^T f16, dt-contiguous: idx = ntg*1024 + l15*64 + ((lg*2+s)^l7)*8
    //   + (dt&1)*4 + r  -> 2x b128 per tile, 2 lanes/slot per 16-lane phase
    __shared__ __align__(16) f16 CVf2[20 * 1024];
    __shared__ __align__(16) float bs[320];    // bias * log2e

    const int tid = threadIdx.x;

    for (int e = tid; e < 64 * 320; e += BLOCK) {
        int d = e / 320, n = e - d * 320;      // coalesced Wcb read
        float w = Wcb[e] * LOG2E;
        short wh = f2bf(w);
        short wl = f2bf(w - bf2f(wh));
        int s = d >> 3;
        int idx = n * 64 + (((s ^ n) & 7) << 3) + (d & 7);
        Wh[idx] = wh;
        Wl[idx] = wl;
    }
    for (int e = tid; e < 320 * 64; e += BLOCK) {
        int c = e >> 6, d = e & 63;       // codevec [320][64] k-major
        int lgs = (c >> 2) & 3, s = (d >> 5) & 1;
        int slot = (lgs * 2 + s) ^ (d & 7);
        CVf2[(c >> 4) * 1024 + (d & 15) * 64 + slot * 8 + ((d >> 4) & 1) * 4 + (c & 3)] =
            (f16)codevec[e];
    }
    for (int e = tid; e < 320; e += BLOCK) bs[e] = bcb[e] * LOG2E;
    __syncthreads();

    const int wid = tid >> 6;
    const int lane = tid & 63;
    const int l15 = lane & 15;          // C column = data row
    const int lg = lane >> 4;           // frag k-group 0..3
    const int l7 = l15 & 7;
    const int u = blockIdx.x * WAVES + wid;   // 0..2047

    // it-invariant LDS element bases
    const int wb0 = l15 * 64 + (((lg ^ l7) & 7) << 3);          // kc=0
    const int wb1 = l15 * 64 + ((((4 + lg) ^ l7) & 7) << 3);    // kc=1
    const int bsb = lg * 4;
    const int cvlo = l15 * 64 + (((lg * 2) ^ l7) << 3);         // s=0
    const int cvhi = l15 * 64 + (((lg * 2 + 1) ^ l7) << 3);     // s=1

    #pragma unroll 1
    for (int it = 0; it < NITER; ++it) {
        const int row0 = u * (NITER * 16) + it * 16;
        const float* xrow = inputs + (size_t)(row0 + l15) * 64;

        // ---- x B-frags, 2 bf16 limbs (no subnormal hazard) ----
        short8 xh[2], xl[2];
        #pragma unroll
        for (int kc = 0; kc < 2; ++kc) {
            float4 a = *(const float4*)(xrow + kc * 32 + lg * 8);
            float4 b = *(const float4*)(xrow + kc * 32 + lg * 8 + 4);
            float xv[8] = {a.x, a.y, a.z, a.w, b.x, b.y, b.z, b.w};
            short8 h, l;
            #pragma unroll
            for (int e = 0; e < 8; ++e) {
                short hh = f2bf(xv[e]);
                h[e] = hh;
                l[e] = f2bf(xv[e] - bf2f(hh));
            }
            xh[kc] = h;
            xl[kc] = l;
        }

        f32x4 cv[4];
        #pragma unroll
        for (int dt = 0; dt < 4; ++dt) cv[dt] = (f32x4){0.f, 0.f, 0.f, 0.f};
        float m_run = 0.f, sum_run = 0.f;
        float m1A, m2A, m1B, m2B;
        int i1A, i1B, cA0, cA1, cA2, cB0, cB1, cB2;

        half_pass<0, true>(Wh, Wl, CVf2, bs, xh, xl, l15, lg,
                           wb0, wb1, bsb, cvlo, cvhi,
                           cv, m_run, sum_run, m1A, m2A, i1A, cA0, cA1, cA2);
        half_pass<160, false>(Wh, Wl, CVf2, bs, xh, xl, l15, lg,
                              wb0, wb1, bsb, cvlo, cvhi,
                              cv, m_run, sum_run, m1B, m2B, i1B, cB0, cB1, cB2);

        // ---- merge halves: global top-2 / argmax ----
        float m1 = m1A;
        int i1 = i1A;
        float m2 = fmaxf(fmaxf(m2A, m2B), fminf(m1A, m1B));
        if (m1B > m1) { m1 = m1B; i1 = i1B; }   // tie -> half A (smaller index)

        float sum = sum_run;
        sum += __shfl_xor(sum, 16, 64);
        sum += __shfl_xor(sum, 32, 64);

        // ---- exact-argmax rescue for near-ties (raw f32, nat units) ----
        // fmaf order (bias first, d ascending) preserved from r3-r16.
        const int mk = mask[u * NITER + it];   // wave-uniform
        int cw = i1;
        const bool flag = mk && (m1 - m2 < TAU2);
        if (__any(flag)) {
            float bv = -INFINITY;
            int bi = 0x7fffffff;
            #pragma unroll 1
            for (int t = 0; t < 8; ++t) {
                int c = (t == 0) ? i1A : (t == 1) ? i1B :
                        (t == 2) ? cA0 : (t == 3) ? cA1 : (t == 4) ? cA2 :
                        (t == 5) ? cB0 : (t == 6) ? cB1 : cB2;
                if (!flag) c = -1;
                if (__any(c >= 0)) {
                    if (c >= 0) {
                        float sacc = bcb[c];
                        #pragma unroll 4
                        for (int q = 0; q < 16; ++q) {
                            float4 xv4 = *(const float4*)(xrow + q * 4);
                            sacc = fmaf(xv4.x, Wcb[(q * 4 + 0) * 320 + c], sacc);
                            sacc = fmaf(xv4.y, Wcb[(q * 4 + 1) * 320 + c], sacc);
                            sacc = fmaf(xv4.z, Wcb[(q * 4 + 2) * 320 + c], sacc);
                            sacc = fmaf(xv4.w, Wcb[(q * 4 + 3) * 320 + c], sacc);
                        }
                        if (sacc > bv || (sacc == bv && c < bi)) { bv = sacc; bi = c; }
                    }
                }
            }
            #pragma unroll
            for (int dx = 16; dx <= 32; dx <<= 1) {
                float vo = __shfl_xor(bv, dx, 64);
                int io = __shfl_xor(bi, dx, 64);
                if (vo > bv || (vo == bv && io < bi)) { bv = vo; bi = io; }
            }
            if (flag) cw = bi;
        }

        // ---- epilogue: mask, normalize, store ----
        const float inv = mk ? (1.0f / sum) : 0.0f;
        float* orow = out_cv + (size_t)(row0 + l15) * 64;
        #pragma unroll
        for (int dt = 0; dt < 4; ++dt) {
            f32x4 v;
            v[0] = cv[dt][0] * inv;
            v[1] = cv[dt][1] * inv;
            v[2] = cv[dt][2] * inv;
            v[3] = cv[dt][3] * inv;
            *(f32x4*)(orow + dt * 16 + lg * 4) = v;
        }
        if (lg == 0) out_cw[row0 + l15] = mk ? (float)cw : 0.0f;
    }
}

extern "C" void kernel_launch(void* const* d_in, const int* in_sizes, int n_in,
                              void* d_out, int out_size, void* d_ws, size_t ws_size,
                              hipStream_t stream) {
    const float* inputs  = (const float*)d_in[0];
    const int*   mask    = (const int*)d_in[1];
    const float* Wcb     = (const float*)d_in[2];
    const float* bcb     = (const float*)d_in[3];
    const float* codevec = (const float*)d_in[4];

    float* out_cv = (float*)d_out;
    float* out_cw = out_cv + (size_t)NROWS * 64;

    vq_mfma<<<GRID, BLOCK, 0, stream>>>(inputs, mask, Wcb, bcb, codevec,
                                        out_cv, out_cw);
}